// Round 1
// 80.638 us; speedup vs baseline: 1.1107x; 1.1107x over previous
//
#include <hip/hip_runtime.h>
#include <hip/hip_fp16.h>
#include <math.h>

#define EPSV 1e-6f
#define TPB 256
#define SLICES 32          // gaussian slices (grid.y)
#define PPT 4              // pixels per thread (2 x float2 packed groups)
#define GRP 2              // PPT/2 vec2 groups
#define GCAP 256           // max gaussians per slice supported in LDS
#define TILE 32            // 2D pixel tile edge (TPB/TILE = 8 rows per pass)
#define CULL_R 5.5f        // cutoff radius multiplier: exp(-0.5*5.5^2) ~ 2.7e-7

typedef float v2f __attribute__((ext_vector_type(2)));

// Per-gaussian packed params: 8 dwords (2 x float4) in LDS:
//   q0 = (na, nb, nc, nd)   q1 = (ne, nf, half2(cr,cg), half2(cb,0))
// w = exp2(na*px^2 + nb*py^2 + nc*px*py + nd*px + ne*py + nf)
// Colors pre-multiplied by alpha.
// NEW: blocks own 32x32 pixel tiles; gaussians whose 5.5*sigma_max circle
// misses the tile box are culled at preprocessing time and survivors are
// compacted in LDS (wave-uniform inner trip count m ~ 30-45 instead of 128).

__device__ __forceinline__ float pack_half2(float a, float b) {
    __half2 h = __floats2half2_rn(a, b);
    union { __half2 h; float f; } u; u.h = h;
    return u.f;
}

__global__ __launch_bounds__(TPB) void splat_fused(
        const float* __restrict__ pos,
        const float* __restrict__ col,
        const float* __restrict__ ls,
        const float* __restrict__ rot,
        const float* __restrict__ alph,
        const int* __restrict__ nact_p,
        const int* __restrict__ hptr,
        const int* __restrict__ wptr,
        float* __restrict__ partial,   // [SLICES][3][P]
        int N, int P, int g_per_slice) {
    __shared__ float4 sh[GCAP * 2];
    __shared__ int s_cnt;

    const int slice = blockIdx.y;
    const int t = threadIdx.x;
    const int W = *wptr;
    const int H = *hptr;

    // ---- 2D tile mapping; fall back to linear strips if grid doesn't factor
    const int ntx = (W + TILE - 1) / TILE;
    const int nty = (H + TILE - 1) / TILE;
    const bool use2d = (W > 1) && (H > 1) && (ntx * nty == (int)gridDim.x);

    float bx0 = -1.f, bx1 = 1.f, by0 = -1.f, by1 = 1.f;  // cull box (uniform)
    int tx = 0, ty = 0;
    if (use2d) {
        tx = blockIdx.x % ntx;
        ty = blockIdx.x / ntx;
        float iw = 2.0f / (float)(W - 1);
        float ih = 2.0f / (float)(H - 1);
        bx0 = -1.f + (float)(tx * TILE) * iw;
        bx1 = -1.f + (float)min(tx * TILE + TILE - 1, W - 1) * iw;
        by0 = -1.f + (float)(ty * TILE) * ih;
        by1 = -1.f + (float)min(ty * TILE + TILE - 1, H - 1) * ih;
    }

    if (t == 0) s_cnt = 0;
    __syncthreads();

    // ---- preprocess + conservative circle-vs-tile cull + LDS compaction ----
    int nact = *nact_p;
    for (int j = t; j < g_per_slice; j += TPB) {
        int g = slice * g_per_slice + j;
        if (g < N && g < nact) {
            float sx = expf(ls[2 * g])     + EPSV;
            float sy = expf(ls[2 * g + 1]) + EPSV;
            float gx = pos[2 * g], gy = pos[2 * g + 1];
            float R  = CULL_R * fmaxf(sx, sy);
            float ddx = fminf(fmaxf(gx, bx0), bx1) - gx;
            float ddy = fminf(fmaxf(gy, by0), by1) - gy;
            if (ddx * ddx + ddy * ddy <= R * R) {
                float r = rot[g];
                float c = cosf(r), s = sinf(r);
                const float K = 0.84932180028801904f;  // sqrt(0.5*log2(e))
                float iA =  K * c / sx;
                float iB =  K * s / sx;
                float iC = -K * s / sy;
                float iD =  K * c / sy;
                float E = -(iA * gx + iB * gy);
                float F = -(iC * gx + iD * gy);
                float a  = iA * iA + iC * iC;
                float b  = iB * iB + iD * iD;
                float cc = 2.0f * (iA * iB + iC * iD);
                float d  = 2.0f * (iA * E + iC * F);
                float e  = 2.0f * (iB * E + iD * F);
                float f  = E * E + F * F;
                float al = alph[g];
                float cr = al * col[3 * g];
                float cg = al * col[3 * g + 1];
                float cb = al * col[3 * g + 2];
                int slot = atomicAdd(&s_cnt, 1);
                sh[2 * slot]     = make_float4(-a, -b, -cc, -d);
                sh[2 * slot + 1] = make_float4(-e, -f, pack_half2(cr, cg),
                                               pack_half2(cb, 0.f));
            }
        }
    }
    __syncthreads();
    const int m = s_cnt;   // wave-uniform survivor count

    // ---- per-thread pixel constants: GRP groups of 2 pixels (float2) ----
    const int base = blockIdx.x * (TPB * PPT);
    v2f px2[GRP], py2[GRP], pxx2[GRP], pyy2[GRP], pxy2[GRP];
    int  pidx[GRP][2];
    bool pact[GRP][2];
#pragma unroll
    for (int k = 0; k < GRP; ++k) {
#pragma unroll
        for (int e = 0; e < 2; ++e) {
            int x, y; bool act;
            if (use2d) {
                x = tx * TILE + (t & (TILE - 1));
                y = ty * TILE + (t >> 5) + (2 * k + e) * (TPB / TILE);
                act = (x < W) && (y < H);
            } else {
                int p = base + t + (2 * k + e) * TPB;
                act = (p < P);
                x = act ? (p % W) : 0;
                y = act ? (p / W) : 0;
            }
            pidx[k][e] = y * W + x;
            pact[k][e] = act;
            float fx = -1.0f + (float)x * (2.0f / (float)(W - 1));
            float fy = -1.0f + (float)y * (2.0f / (float)(H - 1));
            px2[k][e] = fx;  py2[k][e] = fy;
            pxx2[k][e] = fx * fx;  pyy2[k][e] = fy * fy;  pxy2[k][e] = fx * fy;
        }
    }

    v2f accr2[GRP], accg2[GRP], accb2[GRP];
#pragma unroll
    for (int k = 0; k < GRP; ++k) {
        accr2[k] = (v2f)(0.f); accg2[k] = (v2f)(0.f); accb2[k] = (v2f)(0.f);
    }

    // ---- main loop over surviving gaussians only ----
#pragma unroll 2
    for (int g = 0; g < m; ++g) {
        float4 a0 = sh[2 * g];
        float4 a1 = sh[2 * g + 1];

        union { float f; __half2 h; } u01, u2x;
        u01.f = a1.z; u2x.f = a1.w;
        float cr = __low2float(u01.h);
        float cg = __high2float(u01.h);
        float cb = __low2float(u2x.h);

        v2f CA = {a0.x, a0.x}, CB = {a0.y, a0.y}, CC = {a0.z, a0.z};
        v2f CD = {a0.w, a0.w}, CE = {a1.x, a1.x}, CF = {a1.y, a1.y};
        v2f CR = {cr, cr}, CG = {cg, cg}, CBL = {cb, cb};

#pragma unroll
        for (int k = 0; k < GRP; ++k) {
            v2f tt = pxx2[k] * CA + CF;
            tt = pyy2[k] * CB + tt;
            tt = pxy2[k] * CC + tt;
            tt = px2[k]  * CD + tt;
            tt = py2[k]  * CE + tt;
            v2f w;
            w[0] = __builtin_amdgcn_exp2f(tt[0]);
            w[1] = __builtin_amdgcn_exp2f(tt[1]);
            accr2[k] = w * CR  + accr2[k];
            accg2[k] = w * CG  + accg2[k];
            accb2[k] = w * CBL + accb2[k];
        }
    }

    // ---- private partial-sum stores (no atomics, no init needed) ----
    float* dst = partial + (size_t)slice * 3 * P;
#pragma unroll
    for (int k = 0; k < GRP; ++k) {
#pragma unroll
        for (int e = 0; e < 2; ++e) {
            if (pact[k][e]) {
                int p = pidx[k][e];
                dst[p]         = accr2[k][e];
                dst[P + p]     = accg2[k][e];
                dst[2 * P + p] = accb2[k][e];
            }
        }
    }
}

__global__ __launch_bounds__(TPB) void splat_reduce(
        const float4* __restrict__ partial,
        float4* __restrict__ out,
        int total4) {
    int i = blockIdx.x * TPB + threadIdx.x;
    if (i >= total4) return;
    float4 s = make_float4(-1.f, -1.f, -1.f, -1.f);  // render - 1 folded in
#pragma unroll
    for (int sl = 0; sl < SLICES; ++sl) {
        float4 v = partial[(size_t)sl * total4 + i];
        s.x += v.x; s.y += v.y; s.z += v.z; s.w += v.w;
    }
    out[i] = s;
}

extern "C" void kernel_launch(void* const* d_in, const int* in_sizes, int n_in,
                              void* d_out, int out_size, void* d_ws, size_t ws_size,
                              hipStream_t stream) {
    const float* pos  = (const float*)d_in[0];
    const float* col  = (const float*)d_in[1];
    const float* ls   = (const float*)d_in[2];
    const float* rot  = (const float*)d_in[3];
    const float* alph = (const float*)d_in[4];
    const int*   hptr = (const int*)d_in[5];
    const int*   wptr = (const int*)d_in[6];
    const int*   nact = (const int*)d_in[7];

    int N = in_sizes[3];           // rotation has one entry per gaussian
    int P = out_size / 3;          // pixels

    int g_per_slice = (N + SLICES - 1) / SLICES;   // 128 for N=4096
    if (g_per_slice > GCAP) g_per_slice = GCAP;    // capacity guard

    float* partial = (float*)d_ws;  // SLICES * out_size floats (~6.3 MB)

    int px_blocks = (P + TPB * PPT - 1) / (TPB * PPT);   // 16 for P=16384
    dim3 grid(px_blocks, SLICES);
    splat_fused<<<grid, TPB, 0, stream>>>(
        pos, col, ls, rot, alph, nact, hptr, wptr, partial, N, P, g_per_slice);

    int total4 = out_size / 4;
    splat_reduce<<<(total4 + TPB - 1) / TPB, TPB, 0, stream>>>(
        (const float4*)partial, (float4*)d_out, total4);
}